// Round 10
// baseline (311.633 us; speedup 1.0000x reference)
//
#include <hip/hip_runtime.h>
#include <math.h>

// ---------------------------------------------------------------------------
// RTF-SSM block, MI355X. FFT path replaced by:
//   K = impulse response of B(z)/A(z), truncated at 512 taps (Newton
//   power-series inversion, 9 wave-parallel doubling steps).
//   causal conv = Toeplitz-block bf16 MFMA (16x16x32), A-frags prebuilt.
//   GEMMs (65536x256x256) bf16 MFMA with fused bias/gelu/skip/LN/max.
// R6: VALU diet in k_conv. R9: kgen dual-G/uniform-b128 body.
// R10: conv 8ch x 1024t blocks. R13: kgen fused into gemm1 launch.
// R14: gemm2/3 at 512thr/128t (marginal, kept).
// R15: kgen was STILL g1k's critical path (~60us serial chain: 30 segs x
//   48 LDS reads x ~100cy fully-exposed single-outstanding latency):
//   - kgen2x: each wave interleaves TWO channels' chains (independent ->
//     per-load exposure halves). 64 blocks x 2 waves x 2ch; LDS 29952B
//     fits existing union; waves 2-3 exit (no barriers in kgen).
//   - k_pz dissolved: wfb/wdb-convert + xeT-prepad-zero blocks moved INTO
//     g1k launch (consumers >= 2 launches later, race-free); web + maxbuf
//     zero -> tiny k_wenc (web feeds gemm1 same-launch, needs ordering).
// ---------------------------------------------------------------------------

#define BSZ   8
#define SEQ   8192
#define CHN   256
#define ORD   64
#define STAPS 512
#define NDD   17            // d-pairs: covers d = 0..33 (taps to 543 >= 511)
#define PREPAD 544          // history prepad (>= 528 needed), 16-aligned
#define XROW  (PREPAD + SEQ) // 8736 elems per (b,c) row of xe^T
#define MTOT  (BSZ * SEQ)   // 65536
#define YELEMS (MTOT * CHN) // 16777216

#define CT2   1024          // conv t-tile per block
#define CTP   1032          // conv bnc row stride (8-short pad)
#define CROW2 2048          // conv xet row elems (4 x 512 staged)

typedef short s16x8 __attribute__((ext_vector_type(8)));
typedef float f32x4 __attribute__((ext_vector_type(4)));

#define MFMA16(a, b, c) __builtin_amdgcn_mfma_f32_16x16x32_bf16((a), (b), (c), 0, 0, 0)

// async global->LDS 16B: LDS dest = wave-uniform base + lane*16
__device__ __forceinline__ void gll16(const void* g, void* l) {
  __builtin_amdgcn_global_load_lds(
      (const __attribute__((address_space(1))) unsigned int*)g,
      (__attribute__((address_space(3))) unsigned int*)l, 16, 0, 0);
}

// XOR-perm chunk layout: chunk p of (row,h) stored at elems PERMC
#define PERMC(row, h) (((row) * 8 + ((h) ^ ((row) & 7))) * 8)

__device__ __forceinline__ unsigned short f2bf(float f) {
  unsigned u = __float_as_uint(f);
  return (unsigned short)((u + 0x7FFFu + ((u >> 16) & 1u)) >> 16);
}
__device__ __forceinline__ float bf2f(unsigned short h) {
  return __uint_as_float(((unsigned)h) << 16);
}
// tanh-form gelu: x * sigmoid(2*sqrt(2/pi)*(x + 0.044715 x^3)).
// |err| vs exact erf-gelu < ~2e-4, << bf16 noise.
__device__ __forceinline__ float geluf(float x) {
  float x2 = x * x;
  float y = x * __builtin_fmaf(0.0356774081f, x2, 0.7978845608f);
  float e = __builtin_amdgcn_exp2f(-2.8853900818f * y);  // exp(-2y)
  return x * __builtin_amdgcn_rcpf(1.0f + e);
}
__device__ __forceinline__ uint4 packbf8(float4 a, float4 b) {
  uint4 r;
  r.x = (unsigned)f2bf(a.x) | ((unsigned)f2bf(a.y) << 16);
  r.y = (unsigned)f2bf(a.z) | ((unsigned)f2bf(a.w) << 16);
  r.z = (unsigned)f2bf(b.x) | ((unsigned)f2bf(b.y) << 16);
  r.w = (unsigned)f2bf(b.z) | ((unsigned)f2bf(b.w) << 16);
  return r;
}

// ---------------- k_wenc: W_enc fp32->bf16 (feeds gemm1 in next launch) +
// maxxe/maxy zero. grid 36 = 32 web + 4 maxbuf.
__global__ __launch_bounds__(256) void k_wenc(const float* we, unsigned short* web,
                                              uint4* maxbufs) {
  int bx = blockIdx.x, tid = threadIdx.x;
  if (bx < 32) {
    int off = (bx * 256 + tid) * 8;
    float4 f0 = *(const float4*)(we + off);
    float4 f1 = *(const float4*)(we + off + 4);
    *(uint4*)(web + off) = packbf8(f0, f1);
  } else {
    uint4 z; z.x = 0; z.y = 0; z.z = 0; z.w = 0;
    maxbufs[(bx - 32) * 256 + tid] = z;           // maxxe (8KB) + maxy (8KB)
  }
}

// ---------------- kgen2x: Newton inversion of A(z), TWO channels per wave
// (independent chains interleaved -> 2x ILP on the LDS latency chain).
// Dual shifted G copies (aligned b64 reads), uniform b128 coeff reads,
// zero-padded fixed-64 loops -- math identical to the 3x-passing kgen body.
// Per-channel slice (floats): G0=0[584] G1=584[584] Et=1168[64] Asl=1232[64]
// Bsl=1296[64] Kb=1360[512] => 1872. 2 waves x 2ch = 29952B (fits union).
__device__ __forceinline__ void kgen2x(float* smemk, const float* A, const float* Bp,
                                       unsigned short* afr, int blk) {
  int tid = threadIdx.x;
  if (tid >= 128) return;                        // waves 2-3 idle (no barriers)
  int lane = tid & 63, wv = tid >> 6;            // wv in [0,2)
  float* b0 = smemk + (size_t)(wv * 2) * 1872;
  float* b1 = b0 + 1872;
  int c0 = blk * 4 + wv * 2;

  b0[1232 + lane] = A[(size_t)c0 * ORD + lane];
  b1[1232 + lane] = A[(size_t)(c0 + 1) * ORD + lane];
  b0[1296 + lane] = Bp[(size_t)c0 * ORD + lane];
  b1[1296 + lane] = Bp[(size_t)(c0 + 1) * ORD + lane];
  for (int i = lane; i < 1168; i += 64) { b0[i] = 0.f; b1[i] = 0.f; }
  if (lane == 0) { b0[64] = 1.f; b0[584 + 65] = 1.f;
                   b1[64] = 1.f; b1[584 + 65] = 1.f; }

  for (int n = 1; n < STAPS; n <<= 1) {
    int par = (n + lane) & 1;
    int po = par ? 584 : 0;
    int I0 = 64 + n + lane + par;                // even
    const float* GA = b0 + po;
    const float* GB = b1 + po;
    float eA0=0.f,eA1=0.f,eA2=0.f,eA3=0.f, eB0=0.f,eB1=0.f,eB2=0.f,eB3=0.f;
#pragma unroll
    for (int g = 0; g < 16; ++g) {
      float4 avA = *(const float4*)&b0[1232 + 4 * g];
      float4 avB = *(const float4*)&b1[1232 + 4 * g];
      float2 vAA = *(const float2*)&GA[I0 - 4 * g - 2];
      float2 vAB = *(const float2*)&GB[I0 - 4 * g - 2];
      float2 vBA = *(const float2*)&GA[I0 - 4 * g - 4];
      float2 vBB = *(const float2*)&GB[I0 - 4 * g - 4];
      eA0 += avA.x * vAA.y;  eB0 += avB.x * vAB.y;   // u = 4g+1
      eA1 += avA.y * vAA.x;  eB1 += avB.y * vAB.x;   // u = 4g+2
      eA2 += avA.z * vBA.y;  eB2 += avB.z * vBB.y;   // u = 4g+3
      eA3 += avA.w * vBA.x;  eB3 += avB.w * vBB.x;   // u = 4g+4
    }
    b0[1168 + lane] = (eA0 + eA1) + (eA2 + eA3);
    b1[1168 + lane] = (eB0 + eB1) + (eB2 + eB3);
    int nk = (n + 63) >> 6;
    for (int k = 0; k < nk; ++k) {
      int idx = k * 64 + lane;
      int parU = (idx + 1) & 1;
      int pu = parU ? 584 : 0;
      int J0 = 64 + idx - 1 + parU;              // even
      const float* UA = b0 + pu;
      const float* UB = b1 + pu;
      float aA0=0.f,aA1=0.f,aA2=0.f,aA3=0.f, aB0=0.f,aB1=0.f,aB2=0.f,aB3=0.f;
#pragma unroll
      for (int g = 0; g < 16; ++g) {
        float4 evA = *(const float4*)&b0[1168 + 4 * g];
        float4 evB = *(const float4*)&b1[1168 + 4 * g];
        float2 vAA = *(const float2*)&UA[J0 - 4 * g];
        float2 vAB = *(const float2*)&UB[J0 - 4 * g];
        float2 vBA = *(const float2*)&UA[J0 - 4 * g - 2];
        float2 vBB = *(const float2*)&UB[J0 - 4 * g - 2];
        aA0 += evA.x * vAA.y;  aB0 += evB.x * vAB.y; // i = 4g
        aA1 += evA.y * vAA.x;  aB1 += evB.y * vAB.x; // i = 4g+1
        aA2 += evA.z * vBA.y;  aB2 += evB.z * vBB.y; // i = 4g+2
        aA3 += evA.w * vBA.x;  aB3 += evB.w * vBB.x; // i = 4g+3
      }
      if (idx < n) {
        float gA = -((aA0 + aA1) + (aA2 + aA3));
        float gB = -((aB0 + aB1) + (aB2 + aB3));
        b0[64 + n + idx] = gA;  b0[584 + 65 + n + idx] = gA;
        b1[64 + n + idx] = gB;  b1[584 + 65 + n + idx] = gB;
      }
    }
  }

  // K = B conv G, 512 taps out
  for (int k = 0; k < 8; ++k) {
    int t = k * 64 + lane;
    int parB = (t + 1) & 1;
    int pb = parB ? 584 : 0;
    int J0 = 64 + t - 1 + parB;                  // even
    const float* PA = b0 + pb;
    const float* PB = b1 + pb;
    float aA0=0.f,aA1=0.f,aA2=0.f,aA3=0.f, aB0=0.f,aB1=0.f,aB2=0.f,aB3=0.f;
#pragma unroll
    for (int g = 0; g < 16; ++g) {
      float4 bvA = *(const float4*)&b0[1296 + 4 * g];
      float4 bvB = *(const float4*)&b1[1296 + 4 * g];
      float2 vAA = *(const float2*)&PA[J0 - 4 * g];
      float2 vAB = *(const float2*)&PB[J0 - 4 * g];
      float2 vBA = *(const float2*)&PA[J0 - 4 * g - 2];
      float2 vBB = *(const float2*)&PB[J0 - 4 * g - 2];
      aA0 += bvA.x * vAA.y;  aB0 += bvB.x * vAB.y;   // j = 4g
      aA1 += bvA.y * vAA.x;  aB1 += bvB.y * vAB.x;   // j = 4g+1
      aA2 += bvA.z * vBA.y;  aB2 += bvB.z * vBB.y;   // j = 4g+2
      aA3 += bvA.w * vBA.x;  aB3 += bvB.w * vBB.x;   // j = 4g+3
    }
    b0[1360 + t] = (aA0 + aA1) + (aA2 + aA3);
    b1[1360 + t] = (aB0 + aB1) + (aB2 + aB3);
  }

  // Toeplitz MFMA A-fragments (both channels)
  int m = lane & 15, quad = lane >> 4;
  for (int dd = 0; dd < NDD; ++dd) {
    unsigned short vA[8], vB[8];
#pragma unroll
    for (int j = 0; j < 8; ++j) {
      int k = quad * 8 + j;
      int d = 2 * dd + (k >> 4);
      int p = k & 15;
      int s = 16 * d + m - p;
      bool ok = (s >= 0 && s < STAPS);
      vA[j] = f2bf(ok ? b0[1360 + s] : 0.f);
      vB[j] = f2bf(ok ? b1[1360 + s] : 0.f);
    }
    uint4 pkA, pkB;
    pkA.x = (unsigned)vA[0] | ((unsigned)vA[1] << 16);
    pkA.y = (unsigned)vA[2] | ((unsigned)vA[3] << 16);
    pkA.z = (unsigned)vA[4] | ((unsigned)vA[5] << 16);
    pkA.w = (unsigned)vA[6] | ((unsigned)vA[7] << 16);
    pkB.x = (unsigned)vB[0] | ((unsigned)vB[1] << 16);
    pkB.y = (unsigned)vB[2] | ((unsigned)vB[3] << 16);
    pkB.z = (unsigned)vB[4] | ((unsigned)vB[5] << 16);
    pkB.w = (unsigned)vB[6] | ((unsigned)vB[7] << 16);
    *(uint4*)(afr + ((size_t)(c0 * NDD + dd) * 64 + lane) * 8) = pkA;
    *(uint4*)(afr + ((size_t)((c0 + 1) * NDD + dd) * 64 + lane) * 8) = pkB;
  }
}

// --------------- fused launch: [0,64) kgen2x | [64,128) wfb/wdb convert |
// [128,264) xeT prepad zeros | [264,1288) GEMM1.
// GEMM1 (transposed out): xe^T[cout][t] = W_enc x^T + b_enc
// block: 256 cout x 64 t; BK=64; W via global_load_lds, direct-store epilogue.
__global__ __launch_bounds__(256) void k_g1k(const float* A, const float* Bp,
                                             unsigned short* afr,
                                             const float* x, const unsigned short* wb,
                                             const float* benc, unsigned short* xeT,
                                             unsigned int* maxxe,
                                             const float* wf, const float* wd,
                                             unsigned short* wfb, unsigned short* wdb) {
  __shared__ __align__(16) char smem[40960];  // union: gemm1 40960B / kgen 29952B
  if (blockIdx.x < 64) {
    kgen2x((float*)smem, A, Bp, afr, blockIdx.x);
    return;
  }
  if (blockIdx.x < 128) {                     // wfb/wdb: consumers 2 launches later
    int gid = (blockIdx.x - 64) * 256 + threadIdx.x;   // [0,16384)
    int mm = gid >> 13;                       // 0=wf, 1=wd
    int off = (gid & 8191) * 8;
    const float* src = (mm ? wd : wf) + off;
    float4 f0 = *(const float4*)src;
    float4 f1 = *(const float4*)(src + 4);
    *(uint4*)((mm ? wdb : wfb) + off) = packbf8(f0, f1);
    return;
  }
  if (blockIdx.x < 264) {                     // xeT prepad zeros (conv reads, next launch)
    int j0 = (blockIdx.x - 128) * 1024 + threadIdx.x * 4;  // 136*1024 = 139264 exact
    uint4 z; z.x = 0; z.y = 0; z.z = 0; z.w = 0;
#pragma unroll
    for (int u = 0; u < 4; ++u) {
      int j = j0 + u;
      int row = j / 68, cc = j % 68;
      *(uint4*)((char*)xeT + (size_t)row * (XROW * 2) + (size_t)cc * 16) = z;
    }
    return;
  }
  unsigned short* As = (unsigned short*)smem;           // W tile, perm layout
  unsigned short* Bs = (unsigned short*)(smem + 32768); // x tile, perm layout
  int tid = threadIdx.x, lane = tid & 63, wv = tid >> 6;
  int ln15 = lane & 15, hf = lane >> 4;
  size_t t0 = (size_t)(blockIdx.x - 264) * 64; // 1024 gemm blocks
  int b = (int)(t0 >> 13), tin = (int)(t0 & 8191);
  f32x4 acc[4][4];
#pragma unroll
  for (int i = 0; i < 4; ++i)
#pragma unroll
    for (int j = 0; j < 4; ++j) { acc[i][j][0]=0.f; acc[i][j][1]=0.f; acc[i][j][2]=0.f; acc[i][j][3]=0.f; }

  for (int k0 = 0; k0 < CHN; k0 += 64) {
    __syncthreads();
#pragma unroll
    for (int i = 0; i < 8; ++i) {
      int p = 512 * wv + 64 * i + lane;
      int row = p >> 3, h = (p & 7) ^ (row & 7);
      gll16(wb + (size_t)row * CHN + k0 + h * 8, &As[(512 * wv + 64 * i) * 8]);
    }
    {  // x: 64x64 fp32->bf16, 2 chunks/thread
      int row = tid >> 2, hb = (tid & 3) * 2;
      const float* src = x + (t0 + row) * CHN + k0 + hb * 8;
      float4 f0 = *(const float4*)src;
      float4 f1 = *(const float4*)(src + 4);
      float4 f2 = *(const float4*)(src + 8);
      float4 f3 = *(const float4*)(src + 12);
      *(uint4*)&Bs[PERMC(row, hb)]     = packbf8(f0, f1);
      *(uint4*)&Bs[PERMC(row, hb + 1)] = packbf8(f2, f3);
    }
    __syncthreads();
#pragma unroll
    for (int ks = 0; ks < 2; ++ks) {
      s16x8 af[4], bfr[4];
#pragma unroll
      for (int mt = 0; mt < 4; ++mt) {
        int row = 64 * wv + 16 * mt + ln15;
        af[mt] = *(const s16x8*)&As[PERMC(row, ks * 4 + hf)];
      }
#pragma unroll
      for (int nt = 0; nt < 4; ++nt) {
        int row = 16 * nt + ln15;
        bfr[nt] = *(const s16x8*)&Bs[PERMC(row, ks * 4 + hf)];
      }
#pragma unroll
      for (int mt = 0; mt < 4; ++mt)
#pragma unroll
        for (int nt = 0; nt < 4; ++nt)
          acc[mt][nt] = MFMA16(af[mt], bfr[nt], acc[mt][nt]);
    }
  }
  // epilogue: D[m=cout][n=t]; col=lane&15=t, row=quad*4+r
  int quad = hf;
#pragma unroll
  for (int mt = 0; mt < 4; ++mt) {
#pragma unroll
    for (int r = 0; r < 4; ++r) {
      int row = 64 * wv + 16 * mt + 4 * quad + r;
      float bias = benc[row];
      float mv = 0.f;
#pragma unroll
      for (int nt = 0; nt < 4; ++nt) {
        float v = acc[mt][nt][r] + bias;
        int t = tin + 16 * nt + ln15;
        xeT[(size_t)(b * CHN + row) * XROW + PREPAD + t] = f2bf(v);
        mv = fmaxf(mv, fabsf(v));
      }
      mv = fmaxf(mv, __shfl_xor(mv, 1)); mv = fmaxf(mv, __shfl_xor(mv, 2));
      mv = fmaxf(mv, __shfl_xor(mv, 4)); mv = fmaxf(mv, __shfl_xor(mv, 8));
      if (ln15 == 0) atomicMax(&maxxe[b * CHN + row], __float_as_uint(mv));
    }
  }
}

// ------------- conv: y1[t][c] = gelu(FIR(xe) + h0*xe)
// block = 8 ch x 1024 t (512 thr, 8 waves, wave owns 1 channel);
// A-frags in VGPRs; swizzled LDS addrs slide (rotate-8 + (a+512)^64).
__global__ __launch_bounds__(512) void k_conv(const unsigned short* xeT,
                                              const unsigned short* afr,
                                              unsigned short* y1, const float* h0p) {
  __shared__ __align__(16) unsigned short xet[8 * CROW2]; // 32KB
  __shared__ __align__(16) unsigned short bnc[8 * CTP];   // 16.5KB
  int tid = threadIdx.x, lane = tid & 63, wv = tid >> 6;
  int idx = blockIdx.x;                          // grid 2048 = 8b x 32cg x 8tg
  int tg = idx & 7, cg = (idx >> 3) & 31, b = idx >> 8;
  int c0 = cg * 8, t0 = tg * CT2;
  int c = c0 + wv;

  s16x8 afrg[NDD];
  {
    const unsigned short* ap = afr + (size_t)c * (NDD * 512) + (size_t)lane * 8;
#pragma unroll
    for (int dd = 0; dd < NDD; ++dd)
      afrg[dd] = *(const s16x8*)(ap + (size_t)dd * 512);
  }
  {
    int lp = lane ^ ((lane >> 3) & 7);
    const unsigned short* gbase = xeT + (size_t)(b * CHN + c) * XROW + t0;
    unsigned short* lbase = &xet[wv * CROW2];
#pragma unroll
    for (int k = 0; k < 4; ++k)
      gll16(gbase + (size_t)(64 * k + lp) * 8, &lbase[k * 64 * 8]);
  }
  float h0 = h0p[0];

  int n = lane & 15, quad = lane >> 4;
  int qc = quad - ((quad >> 1) << 2);            // 0,1,-2,-1
  const char* xb = (const char*)&xet[wv * CROW2];

  int ad[NDD];
  {
    int cb0 = 2 * n + qc + 68;
#pragma unroll
    for (int dd = 0; dd < NDD; ++dd) {
      int cc = cb0 - 4 * dd;
      ad[dd] = (cc ^ ((cc >> 3) & 7)) * 16;
    }
  }
  int ead;
  {
    int ch = 68 + 2 * n + (quad >> 1);
    ead = (ch ^ ((ch >> 3) & 7)) * 16 + 8 * (quad & 1);
  }
  __syncthreads();

#pragma unroll 1
  for (int s = 0; s < 4; ++s) {
    f32x4 a0, a1;
    a0[0]=0.f; a0[1]=0.f; a0[2]=0.f; a0[3]=0.f;
    a1[0]=0.f; a1[1]=0.f; a1[2]=0.f; a1[3]=0.f;
#pragma unroll
    for (int dd = 0; dd < 16; dd += 2) {
      a0 = MFMA16(afrg[dd],     *(const s16x8*)(xb + ad[dd]),     a0);
      a1 = MFMA16(afrg[dd + 1], *(const s16x8*)(xb + ad[dd + 1]), a1);
    }
    a0 = MFMA16(afrg[16], *(const s16x8*)(xb + ad[16]), a0);
    uint2 xvp = *(const uint2*)(xb + ead);
    unsigned short o[4];
#pragma unroll
    for (int r = 0; r < 4; ++r) {
      float xv = bf2f(((const unsigned short*)&xvp)[r]);
      float v = (a0[r] + a1[r]) + h0 * xv;
      o[r] = f2bf(geluf(v));
    }
    uint2 pw;
    pw.x = (unsigned)o[0] | ((unsigned)o[1] << 16);
    pw.y = (unsigned)o[2] | ((unsigned)o[3] << 16);
    *(uint2*)&bnc[wv * CTP + 256 * s + 16 * n + 4 * quad] = pw;
#pragma unroll
    for (int dd = 16; dd >= 8; --dd) ad[dd] = ad[dd - 8];
#pragma unroll
    for (int dd = 0; dd < 8; ++dd) ad[dd] = (ad[dd] + 512) ^ 64;
    ead = (ead + 512) ^ 64;
  }
  __syncthreads();
  {
    const size_t obase = (size_t)(b * SEQ + t0) * CHN + c0;
    int tb = tid >> 1, h = (tid & 1) * 4;
#pragma unroll
    for (int s = 0; s < 4; ++s) {
      int tl = 256 * s + tb;
      uint2 pk;
      pk.x = (unsigned)bnc[(h + 0) * CTP + tl] | ((unsigned)bnc[(h + 1) * CTP + tl] << 16);
      pk.y = (unsigned)bnc[(h + 2) * CTP + tl] | ((unsigned)bnc[(h + 3) * CTP + tl] << 16);
      *(uint2*)(y1 + obase + (size_t)tl * CHN + h) = pk;
    }
  }
}

// ------ GEMM2: y2n = LN(gelu(y1 W_fc^T + b_fc) + xe)*gamma+beta, in-place y1
// 512 thr / 128-t tile; 8 waves (mh=wv&3, nh=wv>>2); grid 512.
__global__ __launch_bounds__(512) void k_gemm2(const unsigned short* y1,
                                               const unsigned short* wb, const float* bfc,
                                               const unsigned short* xeT, const float* gam,
                                               const float* bet, unsigned short* y2n) {
  __shared__ __align__(16) unsigned short Ws[256 * 64];   // 32768B
  __shared__ __align__(16) unsigned short Asb[128 * 64];  // 16384B
  __shared__ float pl[128][2][2];                         //  2048B
  int tid = threadIdx.x, lane = tid & 63, wv = tid >> 6;
  int ln15 = lane & 15, hf = lane >> 4, quad = hf;
  size_t M0 = (size_t)blockIdx.x * 128;          // grid 512
  int b = (int)(M0 >> 13), tin = (int)(M0 & 8191);
  int mh = wv & 3, nh = wv >> 2;
  f32x4 acc[2][8];
#pragma unroll
  for (int i = 0; i < 2; ++i)
#pragma unroll
    for (int j = 0; j < 8; ++j) { acc[i][j][0]=0.f; acc[i][j][1]=0.f; acc[i][j][2]=0.f; acc[i][j][3]=0.f; }

  for (int k0 = 0; k0 < CHN; k0 += 64) {
    __syncthreads();
#pragma unroll
    for (int i = 0; i < 4; ++i) {               // W: 2048 chunks / 512 thr
      int p = 256 * wv + 64 * i + lane;
      int row = p >> 3, h = (p & 7) ^ (row & 7);
      gll16(wb + (size_t)row * CHN + k0 + h * 8, &Ws[(256 * wv + 64 * i) * 8]);
    }
#pragma unroll
    for (int i = 0; i < 2; ++i) {               // A: 1024 chunks (128 rows)
      int p = 128 * wv + 64 * i + lane;
      int row = p >> 3, h = (p & 7) ^ (row & 7);
      gll16(y1 + (M0 + row) * CHN + k0 + h * 8, &Asb[(128 * wv + 64 * i) * 8]);
    }
    __syncthreads();
#pragma unroll
    for (int ks = 0; ks < 2; ++ks) {
      s16x8 af[2], bfr[8];
#pragma unroll
      for (int mt = 0; mt < 2; ++mt) {
        int row = 32 * mh + 16 * mt + ln15;
        af[mt] = *(const s16x8*)&Asb[PERMC(row, ks * 4 + hf)];
      }
#pragma unroll
      for (int nt = 0; nt < 8; ++nt) {
        int row = 128 * nh + 16 * nt + ln15;
        bfr[nt] = *(const s16x8*)&Ws[PERMC(row, ks * 4 + hf)];
      }
#pragma unroll
      for (int mt = 0; mt < 2; ++mt)
#pragma unroll
        for (int nt = 0; nt < 8; ++nt)
          acc[mt][nt] = MFMA16(af[mt], bfr[nt], acc[mt][nt]);
    }
  }
  float g8[8], be8[8], bf8[8];
#pragma unroll
  for (int nt = 0; nt < 8; ++nt) {
    int col = 128 * nh + 16 * nt + ln15;
    g8[nt] = gam[col]; be8[nt] = bet[col]; bf8[nt] = bfc[col];
  }
#pragma unroll
  for (int mt = 0; mt < 2; ++mt) {
    int mlb = 32 * mh + 16 * mt + 4 * quad;
    uint2 xv2[8];
#pragma unroll
    for (int nt = 0; nt < 8; ++nt) {            // xe skip: 4 consecutive t per lane
      int col = 128 * nh + 16 * nt + ln15;
      xv2[nt] = *(const uint2*)(xeT + (size_t)(b * CHN + col) * XROW + PREPAD + tin + mlb);
    }
#pragma unroll
    for (int r = 0; r < 4; ++r) {
      int ml = mlb + r;
      float s1 = 0.f, s2 = 0.f;
#pragma unroll
      for (int nt = 0; nt < 8; ++nt) {
        float t2 = acc[mt][nt][r] + bf8[nt];
        float xv = bf2f(((const unsigned short*)&xv2[nt])[r]);
        float y2 = geluf(t2) + xv;
        acc[mt][nt][r] = y2;
        s1 += y2; s2 += y2 * y2;
      }
      s1 += __shfl_xor(s1, 1); s2 += __shfl_xor(s2, 1);
      s1 += __shfl_xor(s1, 2); s2 += __shfl_xor(s2, 2);
      s1 += __shfl_xor(s1, 4); s2 += __shfl_xor(s2, 4);
      s1 += __shfl_xor(s1, 8); s2 += __shfl_xor(s2, 8);
      if (ln15 == 0) { pl[ml][nh][0] = s1; pl[ml][nh][1] = s2; }
    }
  }
  __syncthreads();
#pragma unroll
  for (int mt = 0; mt < 2; ++mt) {
#pragma unroll
    for (int r = 0; r < 4; ++r) {
      int ml = 32 * mh + 16 * mt + 4 * quad + r;
      float s1 = pl[ml][0][0] + pl[ml][1][0];
      float s2 = pl[ml][0][1] + pl[ml][1][1];
      float mu = s1 * (1.f / 256.f);
      float var = s2 * (1.f / 256.f) - mu * mu;
      float ri = rsqrtf(var + 1e-5f);
#pragma unroll
      for (int nt = 0; nt < 8; ++nt) {
        int col = 128 * nh + 16 * nt + ln15;
        float yn = (acc[mt][nt][r] - mu) * ri * g8[nt] + be8[nt];
        y2n[(M0 + ml) * CHN + col] = f2bf(yn);
      }
    }
  }
}

// ------------------- GEMM3: y = y2n W_dec^T + b_dec (fp32 out) + maxy atomics
// 512 thr / 128-t tile.
__global__ __launch_bounds__(512) void k_gemm3(const unsigned short* y2n,
                                               const unsigned short* wb, const float* bd,
                                               float* yout, unsigned int* maxy) {
  __shared__ __align__(16) unsigned short Ws[256 * 64];   // 32768B
  __shared__ __align__(16) unsigned short Asb[128 * 64];  // 16384B
  int tid = threadIdx.x, lane = tid & 63, wv = tid >> 6;
  int ln15 = lane & 15, hf = lane >> 4, quad = hf;
  size_t M0 = (size_t)blockIdx.x * 128;          // grid 512
  int b = (int)(M0 >> 13);
  int mh = wv & 3, nh = wv >> 2;
  f32x4 acc[2][8];
#pragma unroll
  for (int i = 0; i < 2; ++i)
#pragma unroll
    for (int j = 0; j < 8; ++j) { acc[i][j][0]=0.f; acc[i][j][1]=0.f; acc[i][j][2]=0.f; acc[i][j][3]=0.f; }

  for (int k0 = 0; k0 < CHN; k0 += 64) {
    __syncthreads();
#pragma unroll
    for (int i = 0; i < 4; ++i) {               // W: 2048 chunks / 512 thr
      int p = 256 * wv + 64 * i + lane;
      int row = p >> 3, h = (p & 7) ^ (row & 7);
      gll16(wb + (size_t)row * CHN + k0 + h * 8, &Ws[(256 * wv + 64 * i) * 8]);
    }
#pragma unroll
    for (int i = 0; i < 2; ++i) {               // A: 1024 chunks (128 rows)
      int p = 128 * wv + 64 * i + lane;
      int row = p >> 3, h = (p & 7) ^ (row & 7);
      gll16(y2n + (M0 + row) * CHN + k0 + h * 8, &Asb[(128 * wv + 64 * i) * 8]);
    }
    __syncthreads();
#pragma unroll
    for (int ks = 0; ks < 2; ++ks) {
      s16x8 af[2], bfr[8];
#pragma unroll
      for (int mt = 0; mt < 2; ++mt) {
        int row = 32 * mh + 16 * mt + ln15;
        af[mt] = *(const s16x8*)&Asb[PERMC(row, ks * 4 + hf)];
      }
#pragma unroll
      for (int nt = 0; nt < 8; ++nt) {
        int row = 128 * nh + 16 * nt + ln15;
        bfr[nt] = *(const s16x8*)&Ws[PERMC(row, ks * 4 + hf)];
      }
#pragma unroll
      for (int mt = 0; mt < 2; ++mt)
#pragma unroll
        for (int nt = 0; nt < 8; ++nt)
          acc[mt][nt] = MFMA16(af[mt], bfr[nt], acc[mt][nt]);
    }
  }
  float bd8[8];
#pragma unroll
  for (int nt = 0; nt < 8; ++nt) bd8[nt] = bd[128 * nh + 16 * nt + ln15];
#pragma unroll
  for (int mt = 0; mt < 2; ++mt)
#pragma unroll
    for (int r = 0; r < 4; ++r) {
      int ml = 32 * mh + 16 * mt + 4 * quad + r;
#pragma unroll
      for (int nt = 0; nt < 8; ++nt) {
        int col = 128 * nh + 16 * nt + ln15;
        float v = acc[mt][nt][r] + bd8[nt];
        acc[mt][nt][r] = v;
        yout[(M0 + ml) * CHN + col] = v;
      }
    }
#pragma unroll
  for (int nt = 0; nt < 8; ++nt) {
    int col = 128 * nh + 16 * nt + ln15;
    float mv = 0.f;
#pragma unroll
    for (int mt = 0; mt < 2; ++mt)
#pragma unroll
      for (int r = 0; r < 4; ++r) mv = fmaxf(mv, fabsf(acc[mt][nt][r]));
    mv = fmaxf(mv, __shfl_xor(mv, 16));
    mv = fmaxf(mv, __shfl_xor(mv, 32));
    if (quad == 0) atomicMax(&maxy[b * CHN + col], __float_as_uint(mv));
  }
}

// ------------------------------------------------------------ h = my/(mx+eps)
__global__ __launch_bounds__(256) void k_hfin(const unsigned int* maxxe,
                                              const unsigned int* maxy, float* hout) {
  int i = blockIdx.x * 256 + threadIdx.x;        // grid 8
  if (i < BSZ * CHN) {
    float mx = __uint_as_float(maxxe[i]);
    float my = __uint_as_float(maxy[i]);
    hout[i] = my / (mx + 1e-6f);
  }
}

// ---------------------------------------------------------------------------
extern "C" void kernel_launch(void* const* d_in, const int* in_sizes, int n_in,
                              void* d_out, int out_size, void* d_ws, size_t ws_size,
                              hipStream_t stream) {
  const float* x   = (const float*)d_in[0];
  const float* A   = (const float*)d_in[1];
  const float* Bp  = (const float*)d_in[2];
  const float* h0  = (const float*)d_in[3];
  const float* We  = (const float*)d_in[4];
  const float* be  = (const float*)d_in[5];
  const float* Wf  = (const float*)d_in[6];
  const float* bfc = (const float*)d_in[7];
  const float* gam = (const float*)d_in[8];
  const float* bet = (const float*)d_in[9];
  const float* Wd  = (const float*)d_in[10];
  const float* bd  = (const float*)d_in[11];

  char* ws = (char*)d_ws;
  unsigned short* y1  = (unsigned short*)(ws + 0);          // 33554432 B
  unsigned short* afr = (unsigned short*)(ws + 33554432);   //  4456448 B
  unsigned short* web = (unsigned short*)(ws + 38010880);   //   131072 B
  unsigned short* wfb = (unsigned short*)(ws + 38141952);
  unsigned short* wdb = (unsigned short*)(ws + 38273024);
  unsigned int*  maxxe = (unsigned int*)(ws + 38404096);    //     8192 B
  unsigned int*  maxy  = (unsigned int*)(ws + 38412288);    //     8192 B

  unsigned short* xeT = (unsigned short*)d_out;             // scratch: 35.8 MB
  float* yout = (float*)d_out;                              // (split g2/g3 keeps
  float* hout = yout + YELEMS;                              //  aliasing race-free)

  k_wenc<<<36, 256, 0, stream>>>(We, web, (uint4*)maxxe);
  k_g1k<<<1288, 256, 0, stream>>>(A, Bp, afr, x, web, be, xeT, maxxe,
                                  Wf, Wd, wfb, wdb);
  k_conv<<<2048, 512, 0, stream>>>(xeT, afr, y1, h0);
  k_gemm2<<<512, 512, 0, stream>>>(y1, wfb, bfc, xeT, gam, bet, y1);
  k_gemm3<<<512, 512, 0, stream>>>(y1, wdb, bd, yout, maxy);
  k_hfin<<<8, 256, 0, stream>>>(maxxe, maxy, hout);
}